// Round 1
// 1174.861 us; speedup vs baseline: 1.0669x; 1.0669x over previous
//
#include <hip/hip_runtime.h>
#include <hip/hip_bf16.h>

// SLSTM recurrence + Linear.  B=1024, T=2048, IN=16, H=128, OUT=1.
// R12 = R11 + phase-restructured step for MFMA||VALU dual-pipe overlap:
//   P1: g,i,f chains interleaved (12 MFMA, pure matrix phase = the floor)
//   P2: o-chain (4 dep MFMA) interleaved 1:5 with packs/exp2 of g,i,f and the
//       c-numerator math, pinned via sched_group_barrier + sched_barrier fences
//   P3: serial tail (cn->ec->hn) covered by the 4 independent accN (x-gate)
//       MFMAs, split 2-before / 2-after the h-write so the pipe drains across
//       the barrier into the next step's zf-read latency window.
// Rationale (R11 counters): MfmaUtil 47.6 + VALUBusy 40.0 ~= 88% ADDITIVE ->
// pipes serialized. In-order issue: dependent MFMA chains stall wave issue, so
// trailing VALU can't overlap unless placed BETWEEN MFMAs in program order.
// Structure: 256 WGs x 512 thr (8 waves = 2/SIMD), 4 batch rows/WG, all 256
// CUs, zero cross-CU traffic. Wave owns col-group wv x 4 gates; accs packed
// 4->1 lane-dense via 3-dpp chain; 1 elem/lane, 7 trans. MFMA floor ~630 us.

#define T_LEN 2048
#define IN_DIM 16
#define CHUNK 32
#define NROWS 4

typedef __attribute__((ext_vector_type(4))) float f32x4;
typedef __attribute__((ext_vector_type(8))) short s16x8;

__device__ __forceinline__ short f2bf(float f) {
    union { float f; unsigned u; } v; v.f = f;
    unsigned r = v.u + 0x7fffu + ((v.u >> 16) & 1u);   // RNE
    return (short)(r >> 16);
}
__device__ __forceinline__ unsigned pk_bf16(float a, float b) {
#if __has_builtin(__builtin_amdgcn_cvt_pk_bf16_f32)
    typedef __attribute__((ext_vector_type(2))) __bf16 bf16x2;
    bf16x2 r = __builtin_amdgcn_cvt_pk_bf16_f32(a, b);
    union { bf16x2 v; unsigned u; } c; c.v = r;
    return c.u;
#else
    return (unsigned)(unsigned short)f2bf(a) | ((unsigned)(unsigned short)f2bf(b) << 16);
#endif
}
// merge quarter-dense regs: lanes 0-3 keep r0; 4-7 <- r1[0-3]; 8-11 <- r2[0-3];
// 12-15 <- r3[0-3].  row_ror:n pulls from lane (i-n) mod 16 (verified R10).
__device__ __forceinline__ float pack4(float r0, float r1, float r2, float r3) {
    int d = __float_as_int(r0);
    d = __builtin_amdgcn_update_dpp(d, __float_as_int(r1), 0x124, 0xF, 0x2, false);
    d = __builtin_amdgcn_update_dpp(d, __float_as_int(r2), 0x128, 0xF, 0x4, false);
    d = __builtin_amdgcn_update_dpp(d, __float_as_int(r3), 0x12C, 0xF, 0x8, false);
    return __int_as_float(d);
}

__global__ __launch_bounds__(512, 2)
void slstm_persistent(const float* __restrict__ x,
                      const float* __restrict__ W_ih,
                      const float* __restrict__ W_hh,
                      const float* __restrict__ b_ih,
                      const float* __restrict__ b_hh,
                      const float* __restrict__ fc_w,
                      const float* __restrict__ fc_b,
                      float* __restrict__ out)
{
    // h: element (col, nb) at shorts[(col>>5)*128 + ((col>>3)&3)*32 + nb*8 + (col&7)]
    // = frag-ordered for the B-operand; the 16 valid reader lanes span all 32
    // banks exactly twice -> conflict-free. 1 KB/buf.
    __shared__ __align__(16) unsigned short h_frag[2][512];
    // x frags [buf][slot][qh 2][n 4][j 8] bf16, dbuf (8 KB)
    __shared__ __align__(16) unsigned short xlds[2][CHUNK][2][4][8];
    __shared__ float red[NROWS];

    const int tid  = threadIdx.x;
    const int lane = tid & 63;
    const int wv   = tid >> 6;          // wave 0..7 = col-group
    const int c16  = lane & 15;
    const int quad = lane >> 4;         // 0..3
    const int b0   = blockIdx.x * NROWS;

    const float kNL2E = -1.44269504f;

    // ---- weights pre-scaled; wave owns col-group wv x 4 gates ----
    s16x8 wfrag[4][5];                  // [g][kf], kf4 = x
    f32x4 biasC[4];
    #pragma unroll
    for (int g = 0; g < 4; ++g) {
        const float scale = (g == 2) ? (2.0f * kNL2E) : kNL2E;
        const int n = g * 128 + wv * 16 + c16;
        #pragma unroll
        for (int kf = 0; kf < 5; ++kf) {
            s16x8 fr;
            #pragma unroll
            for (int j = 0; j < 8; ++j) {
                const int k = kf * 32 + quad * 8 + j;
                float v;
                if (kf < 4) v = W_hh[n * 128 + k];
                else {
                    const int kk = k - 128;
                    v = (kk < IN_DIM) ? W_ih[n * IN_DIM + kk] : 0.0f;
                }
                fr[j] = f2bf(v * scale);
            }
            wfrag[g][kf] = fr;
        }
        #pragma unroll
        for (int r = 0; r < 4; ++r) {
            const int m = g * 128 + wv * 16 + quad * 4 + r;
            biasC[g][r] = (b_ih[m] + b_hh[m]) * scale;
        }
    }

    // zero h buf 0 (h0 = 0); buf 1 fully written at t=0 before first read
    if (tid < 256) ((unsigned*)h_frag)[tid] = 0;

    // ---- packed-lane identity: element (col, nb) ----
    const int e    = c16 >> 2;
    const int nb   = c16 & 3;
    const int col  = wv * 16 + quad * 4 + e;
    const int waddr = (col >> 5) * 128 + ((col >> 3) & 3) * 32 + nb * 8 + (col & 7);
    // h read: valid lanes c16<4 read 16B at v*16 (v = quad*4+c16); others addr 0
    const int hoff = (c16 < 4) ? ((quad * 4 + c16) * 16) : 0;   // bytes within frag
    // x read: valid lanes quad<2 && c16<4
    const bool xv = (quad < 2) && (c16 < 4);
    const int xoff  = xv ? (quad * 64 + c16 * 16) : 0;          // bytes
    const int xmask = xv ? ~0 : 0;

    float c_st = 0.0f, h_ep = 0.0f;

    // ---- prologue: stage chunk 0 -> xlds[0]; chunk 1 -> xreg ----
    f32x4 xreg;
    {
        const int flat4 = tid * 4;
        const int b_loc = flat4 >> 9;
        const int rem   = flat4 & 511;
        const float* xr = x + (size_t)(b0 + b_loc) * (T_LEN * IN_DIM);
        f32x4 v4 = *(const f32x4*)(xr + rem);
        const int slot = rem >> 4, feat = rem & 15;
        unsigned* dst = (unsigned*)&xlds[0][slot][feat >> 3][b_loc][feat & 7];
        dst[0] = pk_bf16(v4[0], v4[1]);
        dst[1] = pk_bf16(v4[2], v4[3]);
        xreg = *(const f32x4*)(xr + CHUNK * IN_DIM + rem);
    }
    __syncthreads();

    // accN = bias + x-MFMA, one step ahead
    f32x4 accN[4];
    {
        s16x8 zx0 = *(const s16x8*)((const char*)xlds + (xoff & xmask));
        #pragma unroll
        for (int g = 0; g < 4; ++g)
            accN[g] = __builtin_amdgcn_mfma_f32_16x16x32_bf16(wfrag[g][4], zx0, biasC[g], 0, 0, 0);
    }

    // step with phase-structured dual-pipe schedule
    auto step_impl = [&](const int RB, const int WB, const int t) {
        const char* hb = (const char*)h_frag[RB];
        s16x8 zf[4];
        #pragma unroll
        for (int kf = 0; kf < 4; ++kf)
            zf[kf] = *(const s16x8*)(hb + hoff + kf * 256);
        // x frag for t+1 (independent of h(t)) — load early
        const int ts  = t + 1;
        const int off = (((ts >> 5) & 1) * 4096 + (ts & 31) * 128 + xoff) & xmask;
        s16x8 zxn = *(const s16x8*)((const char*)xlds + off);

        f32x4 a0 = accN[0], a1 = accN[1], a2 = accN[2], a3 = accN[3];

        // ---- P1: g,i,f chains interleaved (12 MFMA — pure matrix phase) ----
        #pragma unroll
        for (int kf = 0; kf < 4; ++kf) {
            a2 = __builtin_amdgcn_mfma_f32_16x16x32_bf16(wfrag[2][kf], zf[kf], a2, 0, 0, 0);
            a0 = __builtin_amdgcn_mfma_f32_16x16x32_bf16(wfrag[0][kf], zf[kf], a0, 0, 0, 0);
            a1 = __builtin_amdgcn_mfma_f32_16x16x32_bf16(wfrag[1][kf], zf[kf], a1, 0, 0, 0);
        }
        __builtin_amdgcn_sched_barrier(0);

        // ---- P2: o-chain (4 dep MFMA) || packs+exp2 of g,i,f + c-numerator ----
        a3 = __builtin_amdgcn_mfma_f32_16x16x32_bf16(wfrag[3][0], zf[0], a3, 0, 0, 0);
        a3 = __builtin_amdgcn_mfma_f32_16x16x32_bf16(wfrag[3][1], zf[1], a3, 0, 0, 0);
        a3 = __builtin_amdgcn_mfma_f32_16x16x32_bf16(wfrag[3][2], zf[2], a3, 0, 0, 0);
        a3 = __builtin_amdgcn_mfma_f32_16x16x32_bf16(wfrag[3][3], zf[3], a3, 0, 0, 0);
        const float dg = pack4(a2[0], a2[1], a2[2], a2[3]);
        const float eg = __builtin_amdgcn_exp2f(dg);
        const float di = pack4(a0[0], a0[1], a0[2], a0[3]);
        const float ei = __builtin_amdgcn_exp2f(di);
        const float df = pack4(a1[0], a1[1], a1[2], a1[3]);
        const float ef = __builtin_amdgcn_exp2f(df);
        const float af  = 1.0f + ef;
        const float t1  = (1.0f + ei) * (1.0f + eg);
        const float num = fmaf(c_st, t1, (1.0f - eg) * af);
        const float den = af * t1;
        // pin the interleave: 1 MFMA : 5 VALU, x4 — the o-chain's dep-stall
        // cycles become VALU issue slots (the whole point of this round)
        #pragma unroll
        for (int kq = 0; kq < 4; ++kq) {
            __builtin_amdgcn_sched_group_barrier(0x008, 1, 0);  // 1 MFMA
            __builtin_amdgcn_sched_group_barrier(0x002, 5, 0);  // 5 VALU
        }
        __builtin_amdgcn_sched_barrier(0);

        // ---- P3: serial tail covered by accN refresh (independent MFMAs) ----
        accN[0] = __builtin_amdgcn_mfma_f32_16x16x32_bf16(wfrag[0][4], zxn, biasC[0], 0, 0, 0);
        accN[1] = __builtin_amdgcn_mfma_f32_16x16x32_bf16(wfrag[1][4], zxn, biasC[1], 0, 0, 0);
        const float cn = num * __builtin_amdgcn_rcpf(den);
        c_st = cn;
        const float ec = __builtin_amdgcn_exp2f(fminf(cn * (2.0f * kNL2E), 40.f));
        const float dojj = pack4(a3[0], a3[1], a3[2], a3[3]);
        const float eo = __builtin_amdgcn_exp2f(dojj);
        const float hn = (1.0f - ec) * __builtin_amdgcn_rcpf((1.0f + eo) * (1.0f + ec));
        h_ep = hn;
        h_frag[WB][waddr] = (unsigned short)f2bf(hn);   // one ds_write_b16
        // last two accN MFMAs drain across the barrier into the next step's
        // zf-read latency window
        accN[2] = __builtin_amdgcn_mfma_f32_16x16x32_bf16(wfrag[2][4], zxn, biasC[2], 0, 0, 0);
        accN[3] = __builtin_amdgcn_mfma_f32_16x16x32_bf16(wfrag[3][4], zxn, biasC[3], 0, 0, 0);
        __syncthreads();
    };

    for (int t = 0; t < T_LEN; t += 2) {
        step_impl(0, 1, t);

        // ---- spread x maintenance ----
        const int iter  = (t >> 1) & 15;
        const int cbase = t & ~(CHUNK - 1);
        if (iter < 2) {
            if (cbase + CHUNK < T_LEN) {
                const int flat4 = tid * 4;
                const int b_loc = flat4 >> 9;
                const int rem   = flat4 & 511;
                const int slot = rem >> 4, feat = rem & 15;
                const int nb1 = ((cbase >> 5) + 1) & 1;
                unsigned* dst = (unsigned*)&xlds[nb1][slot][feat >> 3][b_loc][(feat & 7) + 2 * iter];
                dst[0] = pk_bf16(xreg[2 * iter], xreg[2 * iter + 1]);
            }
        } else if (iter == 8) {
            const int tnext = cbase + 2 * CHUNK;
            if (tnext < T_LEN) {
                const int flat4 = tid * 4;
                const int b_loc = flat4 >> 9;
                const int rem   = flat4 & 511;
                xreg = *(const f32x4*)(x + (size_t)(b0 + b_loc) * (T_LEN * IN_DIM)
                                         + (size_t)tnext * IN_DIM + rem);
            }
        }

        step_impl(1, 0, t + 1);
    }

    // ---- epilogue: out[b] = sum_cols h * fc_w + fc_b ----
    float v = h_ep * fc_w[col];
    v += __shfl_xor(v, 4);
    v += __shfl_xor(v, 8);
    v += __shfl_xor(v, 16);
    v += __shfl_xor(v, 32);
    if (tid < NROWS) red[tid] = 0.0f;
    __syncthreads();
    if (lane < NROWS) atomicAdd(&red[nb], v);
    __syncthreads();
    if (tid < NROWS) out[b0 + tid] = red[tid] + fc_b[0];
}

extern "C" void kernel_launch(void* const* d_in, const int* in_sizes, int n_in,
                              void* d_out, int out_size, void* d_ws, size_t ws_size,
                              hipStream_t stream) {
    const float* x    = (const float*)d_in[0];
    const float* W_ih = (const float*)d_in[1];
    const float* W_hh = (const float*)d_in[2];
    const float* b_ih = (const float*)d_in[3];
    const float* b_hh = (const float*)d_in[4];
    const float* fc_w = (const float*)d_in[5];
    const float* fc_b = (const float*)d_in[6];
    float* out = (float*)d_out;

    slstm_persistent<<<256, 512, 0, stream>>>(x, W_ih, W_hh, b_ih, b_hh, fc_w, fc_b, out);
}